// Round 1
// 123.423 us; speedup vs baseline: 1.0310x; 1.0310x over previous
//
#include <hip/hip_runtime.h>

// DilatedSpatialAttention — round 17.
// R16 result: 127.26us (neutral vs R14's 126.7) => occupancy (3 vs 5 blk/CU)
// and halo traffic (1.5x vs 2.0x) are NOT the conv limiter. Residual theory:
// staging is 8 serialized load->waitcnt->ds_write round-trips per thread.
// R17: async DMA staging via __builtin_amdgcn_global_load_lds width=16
// (layout already wave-uniform-base + lane*16). OOB rows: skipped at issue
// (block-uniform branch) and skipped at tap time (acc += w*0 is bit-exact,
// bias starts +0) => conv BIT-IDENTICAL => absmax stays exactly 1.220703e-4.
// Attn BYTE-IDENTICAL to R13/R14/R16 (K direct from L2, V^T dbuf LDS,
// fixed-max log2-domain softmax, Dsum via mfma, XCD swizzle) — it sits at
// its ~10-12us roofline (MFMA 2.7us, exp2 3.4us, 50MB traffic 8us).
// Measurement model: 2x 256MiB harness poison fills (~87us) + conv + attn.
#define B_    16
#define HH    32
#define WW    32
#define CC    256
#define HEADS 8
#define HD    32
#define S_    1024
#define KT    128                 // keys per tile
#define NITER (S_ / KT)           // 8
#define SCALE_L2E 0.25503486f     // 32^-0.5 * log2(e)  (pre-folded into Kws)

typedef unsigned short u16;
typedef unsigned int   u32;
typedef __attribute__((ext_vector_type(8))) short short8;  // 8 bf16 (A/B frag)
typedef __attribute__((ext_vector_type(4))) float f32x4;   // C/D frag

__device__ __forceinline__ u16 f2bf(float f) {             // RNE
    u32 x = __float_as_uint(f);
    return (u16)((x + 0x7fffu + ((x >> 16) & 1u)) >> 16);
}
__device__ __forceinline__ u32 pack2bf(float lo, float hi) {
    return (u32)f2bf(lo) | ((u32)f2bf(hi) << 16);
}

// async global->LDS DMA, 16B per lane; LDS dest is wave-uniform base + lane*16
#define GLD_LDS16(gp, lp)                                                 \
    __builtin_amdgcn_global_load_lds(                                     \
        (const __attribute__((address_space(1))) void*)(gp),              \
        (__attribute__((address_space(3))) void*)(lp), 16, 0, 0)

// ---------------------------------------------------------------------------
// Kernel 1: depthwise dilated 3x3 (dil=2, SAME) conv, LDS-staged, 32KB tile.
// Block = (tensor t, batch b, y-tile of 4 rows, head-group g of 32 ch).
// LDS: 8 rows (y0-2..y0+5) x 32 x x 8 float4 = 32768 B -> 5 blocks/CU.
// Staging: 8x global_load_lds dwordx4 per thread-slot, issued back-to-back
// (uniform row-validity branch), single vmcnt(0) drain at the barrier.
// Compute: 4 outputs/thread, <=9 LDS taps each; y-OOB taps skipped
// (bit-identical to adding w*0). Output head-major bf16
// ws[(b*8+h)*1024+s][d]; K pre-scaled by SCALE_L2E.
// ---------------------------------------------------------------------------
__global__ __launch_bounds__(256, 5) void dw_conv_kernel(
    const float* __restrict__ key_in, const float* __restrict__ value,
    const float* __restrict__ ck, const float* __restrict__ cb,
    u16* __restrict__ Kws, u16* __restrict__ Vws)
{
    __shared__ float4 tile[2048];      // [r 0..7][x 0..31][c 0..7]

    const int tid = threadIdx.x;
    const int blk = blockIdx.x;        // 2048 = 2 t x 16 b x 8 yt x 8 g
    const int g  = blk & 7;            // 32-ch head group (head h = g)
    const int yt = (blk >> 3) & 7;     // y tile (4 rows)
    const int b  = (blk >> 6) & 15;
    const int t  = blk >> 10;          // 0 = key, 1 = value (block-uniform)
    const float4* __restrict__ src4 = (const float4*)(t ? value : key_in);
    const int y0 = yt * 4;

    // ---- stage halo'd tile: 8 rows, async DMA, no VGPR round-trip ----
    // slot = tid + i*256 -> row r = i (block-uniform), x=(tid>>3)&31, c=tid&7.
    // Per wave: LDS base (i*256 + wv*64)*16 + lane*16  (HW-required layout).
    {
        const int x  = (tid >> 3) & 31;
        const int cc = tid & 7;
        #pragma unroll
        for (int i = 0; i < 8; i++) {
            int yy = y0 - 2 + i;                       // block-uniform
            if (yy >= 0 && yy < HH) {
                const float4* gp = src4 +
                    ((((size_t)b * HH + yy) * WW + x) * 64 + g * 8 + cc);
                GLD_LDS16(gp, &tile[tid + i * 256]);
            }
            // OOB rows: LDS left stale; compute skips those taps entirely.
        }
    }

    // ---- per-thread fixed channel quad c = tid&7: weights + bias once ----
    const int c = tid & 7;
    float4 w9[9];
    #pragma unroll
    for (int j = 0; j < 9; j++)
        w9[j] = *(const float4*)(ck + j * CC + g * 32 + c * 4);
    const float4 bias = *(const float4*)(cb + g * 32 + c * 4);

    __syncthreads();                   // vmcnt(0) drain: all DMA landed

    // ---- compute 4 outputs/thread from LDS (bias-first, kh/kw ascending,
    //      OOB-skip on BOTH axes: identical FMA value-sequence to R14/R16,
    //      since skipped y-taps contributed exactly +0) ----
    #pragma unroll
    for (int i = 0; i < 4; i++) {
        int o = tid + i * 256;         // o = (ry*32 + x)*8 + c, ry == i
        int x = (o >> 3) & 31;
        const int ry = i;
        float4 acc = bias;
        #pragma unroll
        for (int kh = 0; kh < 3; kh++) {
            int yy = y0 + ry - 2 + 2 * kh;             // block-uniform
            if (yy < 0 || yy >= HH) continue;          // stale-LDS rows never read
            #pragma unroll
            for (int kw = 0; kw < 3; kw++) {
                int xx = x - 2 + 2 * kw;
                if (xx < 0 || xx >= WW) continue;      // per-lane, as before
                float4 v = tile[((ry + 2 * kh) * 32 + xx) * 8 + c];
                float4 w = w9[kh * 3 + kw];
                acc.x += w.x * v.x; acc.y += w.y * v.y;
                acc.z += w.z * v.z; acc.w += w.w * v.w;
            }
        }
        int spix = (y0 + ry) * WW + x;
        size_t off = (((size_t)(b * HEADS + g)) * S_ + spix) * HD + c * 4;
        if (t == 0)
            *(uint2*)&Kws[off] = make_uint2(pack2bf(acc.x * SCALE_L2E, acc.y * SCALE_L2E),
                                            pack2bf(acc.z * SCALE_L2E, acc.w * SCALE_L2E));
        else
            *(uint2*)&Vws[off] = make_uint2(pack2bf(acc.x, acc.y), pack2bf(acc.z, acc.w));
    }
}

// ---------------------------------------------------------------------------
// Kernel 2: MFMA flash attention (BYTE-IDENTICAL to R13/R14/R16). K-fragments
// direct from global/L2 (Kws[key][d] == A-frag layout), issued pre-barrier.
// V^T double-buffered in LDS with per-32-chunk column permutation
// pos(Q,t',r) <- key(t',Q,r). Fixed-max softmax in log2 domain; denominator
// via mfma(ones, pk, Dsum). bh = blk&127 XCD swizzle.
// ---------------------------------------------------------------------------
__global__ __launch_bounds__(256, 4) void attn_kernel(
    const float* __restrict__ query,
    const u16* __restrict__ Kws, const u16* __restrict__ Vws,
    float* __restrict__ out)
{
    __shared__ __align__(16) u16 Vtlds[2][HD][KT + 8];  // 2 x 8.5 KB

    const int tid  = threadIdx.x;
    const int lane = tid & 63;
    const int wv   = tid >> 6;
    const int q15  = lane & 15;
    const int quad = lane >> 4;

    const int blk = blockIdx.x;        // 1024 blocks
    const int bh  = blk & 127;         // XCD swizzle: same bh -> same blk%8
    const int qt  = blk >> 7;
    const int b = bh >> 3, h = bh & 7;
    const int q0w = qt * 128 + wv * 32;  // wave's first query

    // ---- Q fragments: 2 x (16 rows x 32 d), fp32 global -> bf16 regs ----
    short8 qf[2];
    #pragma unroll
    for (int f = 0; f < 2; f++) {
        const float* qp = query + ((size_t)(b * S_ + q0w + f * 16 + q15)) * CC
                          + h * HD + quad * 8;
        float4 a = *(const float4*)(qp);
        float4 c = *(const float4*)(qp + 4);
        short8 v;
        v[0] = (short)f2bf(a.x); v[1] = (short)f2bf(a.y);
        v[2] = (short)f2bf(a.z); v[3] = (short)f2bf(a.w);
        v[4] = (short)f2bf(c.x); v[5] = (short)f2bf(c.y);
        v[6] = (short)f2bf(c.z); v[7] = (short)f2bf(c.w);
        qf[f] = v;
    }

    short8 ones;                       // bf16 1.0 = 0x3F80
    #pragma unroll
    for (int j = 0; j < 8; j++) ones[j] = (short)0x3F80;

    const u16* Kg = Kws + (size_t)bh * S_ * HD;
    const u16* Vg = Vws + (size_t)bh * S_ * HD;

    // ---- V staging geometry (fixed per thread) ----
    const int vg  = tid >> 3, vs4 = tid & 7;
    const int vc = vg >> 3, vw = vg & 7;
    const int vt2 = (vw >> 2) & 1, vqd = vw & 3;
    const int vpg = (vc << 5) | (vqd << 3) | (vt2 << 2);   // permuted col base

    uint2 vr0, vr1, vr2, vr3;          // V stage regs (32 B/thread)

    auto issue_v_loads = [&](int kt0) {
        const uint2* vsrc = (const uint2*)(Vg + (size_t)(kt0 + 4 * vg) * HD + 4 * vs4);
        vr0 = vsrc[0]; vr1 = vsrc[8]; vr2 = vsrc[16]; vr3 = vsrc[24];
    };
    auto write_lds = [&](int p) {
        u32 a, bb;
        a  = __builtin_amdgcn_perm(vr1.x, vr0.x, 0x05040100u);
        bb = __builtin_amdgcn_perm(vr3.x, vr2.x, 0x05040100u);
        *(uint2*)&Vtlds[p][4 * vs4 + 0][vpg] = make_uint2(a, bb);
        a  = __builtin_amdgcn_perm(vr1.x, vr0.x, 0x07060302u);
        bb = __builtin_amdgcn_perm(vr3.x, vr2.x, 0x07060302u);
        *(uint2*)&Vtlds[p][4 * vs4 + 1][vpg] = make_uint2(a, bb);
        a  = __builtin_amdgcn_perm(vr1.y, vr0.y, 0x05040100u);
        bb = __builtin_amdgcn_perm(vr3.y, vr2.y, 0x05040100u);
        *(uint2*)&Vtlds[p][4 * vs4 + 2][vpg] = make_uint2(a, bb);
        a  = __builtin_amdgcn_perm(vr1.y, vr0.y, 0x07060302u);
        bb = __builtin_amdgcn_perm(vr3.y, vr2.y, 0x07060302u);
        *(uint2*)&Vtlds[p][4 * vs4 + 3][vpg] = make_uint2(a, bb);
    };

    f32x4 Ot[2][2];                    // [frag][dhalf], C-layout (rows = d)
    f32x4 Dsum[2];                     // denominator accumulator
    #pragma unroll
    for (int f = 0; f < 2; f++) {
        Ot[f][0] = (f32x4)0.f; Ot[f][1] = (f32x4)0.f; Dsum[f] = (f32x4)0.f;
    }

    issue_v_loads(0);
    write_lds(0);                      // prologue: buffer 0

    for (int it = 0; it < NITER; it++) {
        const int p = it & 1;
        const int kt0 = it * KT;

        // ---- K fragments: direct global/L2, issued pre-barrier ----
        short8 kfr0[4], kfr1[4];
        #pragma unroll
        for (int c = 0; c < 4; c++) {
            kfr0[c] = *(const short8*)(Kg + (size_t)(kt0 + c * 32 + q15) * HD + quad * 8);
            kfr1[c] = *(const short8*)(Kg + (size_t)(kt0 + c * 32 + 16 + q15) * HD + quad * 8);
        }
        if (it + 1 < NITER) issue_v_loads((it + 1) * KT);  // next V tile in flight
        __syncthreads();               // buf p writes visible; prev readers of 1-p done

        // ---- chunk-fused: QK -> exp2 -> pack -> PV per 32 keys ----
        #pragma unroll
        for (int c = 0; c < 4; c++) {
            short8 vf0 = *(const short8*)&Vtlds[p][q15][c * 32 + quad * 8];
            short8 vf1 = *(const short8*)&Vtlds[p][16 + q15][c * 32 + quad * 8];
            #pragma unroll
            for (int f = 0; f < 2; f++) {
                f32x4 s0 = __builtin_amdgcn_mfma_f32_16x16x32_bf16(kfr0[c], qf[f], (f32x4)0.f, 0, 0, 0);
                f32x4 s1 = __builtin_amdgcn_mfma_f32_16x16x32_bf16(kfr1[c], qf[f], (f32x4)0.f, 0, 0, 0);
                #pragma unroll
                for (int r = 0; r < 4; r++) {
                    s0[r] = __builtin_amdgcn_exp2f(s0[r]);
                    s1[r] = __builtin_amdgcn_exp2f(s1[r]);
                }
                union { u32 u[4]; short8 s8; } pk;   // bf16-truncate pack
                pk.u[0] = __builtin_amdgcn_perm(__float_as_uint(s0[1]),
                                                __float_as_uint(s0[0]), 0x07060302u);
                pk.u[1] = __builtin_amdgcn_perm(__float_as_uint(s0[3]),
                                                __float_as_uint(s0[2]), 0x07060302u);
                pk.u[2] = __builtin_amdgcn_perm(__float_as_uint(s1[1]),
                                                __float_as_uint(s1[0]), 0x07060302u);
                pk.u[3] = __builtin_amdgcn_perm(__float_as_uint(s1[3]),
                                                __float_as_uint(s1[2]), 0x07060302u);
                Ot[f][0] = __builtin_amdgcn_mfma_f32_16x16x32_bf16(vf0, pk.s8, Ot[f][0], 0, 0, 0);
                Ot[f][1] = __builtin_amdgcn_mfma_f32_16x16x32_bf16(vf1, pk.s8, Ot[f][1], 0, 0, 0);
                Dsum[f]  = __builtin_amdgcn_mfma_f32_16x16x32_bf16(ones, pk.s8, Dsum[f], 0, 0, 0);
            }
        }
        if (it + 1 < NITER) write_lds((it + 1) & 1);      // idle buffer
    }

    // ---- epilogue: O^T[d][q] / Dsum[q] -> out[b][q][h*32+d] ----
    #pragma unroll
    for (int f = 0; f < 2; f++) {
        float inv = 1.0f / Dsum[f][0];
        int qg = q0w + f * 16 + q15;
        float* op = out + ((size_t)(b * S_ + qg)) * CC + h * HD;
        #pragma unroll
        for (int h2 = 0; h2 < 2; h2++)
            #pragma unroll
            for (int r = 0; r < 4; r++)
                op[h2 * 16 + quad * 4 + r] = Ot[f][h2][r] * inv;
    }
}

// ---------------------------------------------------------------------------
extern "C" void kernel_launch(void* const* d_in, const int* in_sizes, int n_in,
                              void* d_out, int out_size, void* d_ws, size_t ws_size,
                              hipStream_t stream)
{
    const float* query  = (const float*)d_in[0];
    const float* key_in = (const float*)d_in[1];
    const float* value  = (const float*)d_in[2];
    const float* ck     = (const float*)d_in[3];
    const float* cb     = (const float*)d_in[4];
    float* out = (float*)d_out;

    u16* Kws = (u16*)d_ws;                               // 8.39 MB
    u16* Vws = Kws + (size_t)B_ * HEADS * S_ * HD;       // 8.39 MB

    // LDS-staged conv: 2 t x 16 b x 8 y-tiles x 8 ch-groups = 2048 blocks.
    dw_conv_kernel<<<2048, 256, 0, stream>>>(
        key_in, value, ck, cb, Kws, Vws);

    // 128 queries per block (4 waves x 32): grid = 131072/128 = 1024 blocks.
    // blk decode is XCD-swizzled inside the kernel (bh = blk&127).
    attn_kernel<<<(B_ * HEADS * S_) / 128, 256, 0, stream>>>(
        query, Kws, Vws, out);
}